// Round 1
// baseline (10508.932 us; speedup 1.0000x reference)
//
#include <hip/hip_runtime.h>
#include <math.h>

#define N_LAYERS 4
#define DMODEL 1024
#define DINNER 2048
#define DSTATE 16
#define DTRANK 64
#define DCONV 4
#define NBATCH 2
#define LSEQ 2048
#define LNEPS 1e-5f
#define ROWS (NBATCH * LSEQ)   // 4096

// ---------------- LayerNorm (row per block, 1024 cols, 256 threads) ----------
__global__ __launch_bounds__(256) void ln_kernel(
    const float* __restrict__ src, float* __restrict__ res_copy,
    const float* __restrict__ w, const float* __restrict__ b,
    float* __restrict__ out) {
  int row = blockIdx.x;
  int t = threadIdx.x;
  const float4* srow = (const float4*)(src + (size_t)row * DMODEL);
  float4 v = srow[t];
  if (res_copy) ((float4*)(res_copy + (size_t)row * DMODEL))[t] = v;
  float s = v.x + v.y + v.z + v.w;
  float sq = v.x * v.x + v.y * v.y + v.z * v.z + v.w * v.w;
  #pragma unroll
  for (int o = 32; o >= 1; o >>= 1) {
    s += __shfl_xor(s, o);
    sq += __shfl_xor(sq, o);
  }
  __shared__ float ss[4], ssq[4];
  int wid = t >> 6, lane = t & 63;
  if (lane == 0) { ss[wid] = s; ssq[wid] = sq; }
  __syncthreads();
  s = ss[0] + ss[1] + ss[2] + ss[3];
  sq = ssq[0] + ssq[1] + ssq[2] + ssq[3];
  float mu = s * (1.f / DMODEL);
  float var = sq * (1.f / DMODEL) - mu * mu;
  float rs = rsqrtf(var + LNEPS);
  float4 wv = ((const float4*)w)[t];
  float4 bv = ((const float4*)b)[t];
  float4 o4;
  o4.x = (v.x - mu) * rs * wv.x + bv.x;
  o4.y = (v.y - mu) * rs * wv.y + bv.y;
  o4.z = (v.z - mu) * rs * wv.z + bv.z;
  o4.w = (v.w - mu) * rs * wv.w + bv.w;
  ((float4*)(out + (size_t)row * DMODEL))[t] = o4;
}

__device__ __forceinline__ float softplus_f(float x) {
  return x > 20.f ? x : log1pf(expf(x));
}

// ---------------- Generic fp32 GEMM: C[M,N] = act(A[M,K] @ W[N,K]^T + bias) (+add)
// 64x64 block tile, 256 threads, 4x4 per thread, K-tile 16.
template<int ACT, bool ADD, bool BIAS>
__global__ __launch_bounds__(256) void gemm_kernel(
    const float* __restrict__ A, int lda,
    const float* __restrict__ W,          // [N, K] row-major
    float* __restrict__ C, int ldc,
    int N, int K,
    const float* __restrict__ bias,
    const float* __restrict__ addsrc, int ldadd) {
  __shared__ float As[16][68];  // [k][row], pad keeps float4 alignment + banks spread
  __shared__ float Ws[16][68];
  int t = threadIdx.x;
  int tx = t & 15, ty = t >> 4;
  int m0 = blockIdx.y * 64, n0 = blockIdx.x * 64;
  int lk = t & 15;      // k within tile
  int lrow = t >> 4;    // base row 0..15, step 16
  float acc[4][4] = {{0.f}};
  for (int k0 = 0; k0 < K; k0 += 16) {
    #pragma unroll
    for (int i = 0; i < 4; i++) {
      int r = lrow + i * 16;
      As[lk][r] = A[(size_t)(m0 + r) * lda + k0 + lk];
    }
    #pragma unroll
    for (int i = 0; i < 4; i++) {
      int r = lrow + i * 16;
      int n = n0 + r;
      Ws[lk][r] = (n < N) ? W[(size_t)n * K + k0 + lk] : 0.f;
    }
    __syncthreads();
    #pragma unroll
    for (int kk = 0; kk < 16; kk++) {
      float4 av = *(const float4*)&As[kk][ty * 4];
      float4 bv = *(const float4*)&Ws[kk][tx * 4];
      float a[4] = {av.x, av.y, av.z, av.w};
      float bb[4] = {bv.x, bv.y, bv.z, bv.w};
      #pragma unroll
      for (int i = 0; i < 4; i++)
        #pragma unroll
        for (int j = 0; j < 4; j++)
          acc[i][j] = fmaf(a[i], bb[j], acc[i][j]);
    }
    __syncthreads();
  }
  #pragma unroll
  for (int i = 0; i < 4; i++) {
    int m = m0 + ty * 4 + i;
    #pragma unroll
    for (int j = 0; j < 4; j++) {
      int n = n0 + tx * 4 + j;
      if (n < N) {
        float vv = acc[i][j];
        if (BIAS) vv += bias[n];
        if (ACT == 1) vv = softplus_f(vv);
        if (ADD) vv += addsrc[(size_t)m * ldadd + n];
        C[(size_t)m * ldc + n] = vv;
      }
    }
  }
}

// ---------------- causal depthwise conv1d + SiLU -----------------------------
__global__ __launch_bounds__(256) void conv_silu_kernel(
    const float* __restrict__ xz, const float* __restrict__ cw,
    const float* __restrict__ cb, float* __restrict__ x) {
  int tid = blockIdx.x * 256 + threadIdx.x;   // over ROWS * DINNER/4
  int dv = tid & (DINNER / 4 - 1);
  int row = tid / (DINNER / 4);
  int l = row & (LSEQ - 1);
  int d = dv * 4;
  float acc0 = cb[d], acc1 = cb[d + 1], acc2 = cb[d + 2], acc3 = cb[d + 3];
  #pragma unroll
  for (int k = 0; k < DCONV; k++) {
    int ll = l - (DCONV - 1) + k;
    if (ll >= 0) {
      const float4 xv = *(const float4*)(xz + (size_t)(row - (DCONV - 1) + k) * (2 * DINNER) + d);
      acc0 = fmaf(xv.x, cw[(d + 0) * DCONV + k], acc0);
      acc1 = fmaf(xv.y, cw[(d + 1) * DCONV + k], acc1);
      acc2 = fmaf(xv.z, cw[(d + 2) * DCONV + k], acc2);
      acc3 = fmaf(xv.w, cw[(d + 3) * DCONV + k], acc3);
    }
  }
  float4 o;
  o.x = acc0 / (1.f + __expf(-acc0));
  o.y = acc1 / (1.f + __expf(-acc1));
  o.z = acc2 / (1.f + __expf(-acc2));
  o.w = acc3 / (1.f + __expf(-acc3));
  *(float4*)(x + (size_t)row * DINNER + d) = o;
}

// ---------------- selective scan: thread per (b,d,s), sequential over L ------
__global__ __launch_bounds__(256) void scan_kernel(
    const float* __restrict__ delta, const float* __restrict__ u,
    const float* __restrict__ xdbl, const float* __restrict__ xz,
    const float* __restrict__ A_log, const float* __restrict__ Dp,
    float* __restrict__ y) {
  int tid = blockIdx.x * 256 + threadIdx.x;  // 65536 total
  int s = tid & 15;
  int d = (tid >> 4) & (DINNER - 1);
  int b = tid >> 15;
  float Aval = -__expf(A_log[d * DSTATE + s]);
  float Dval = Dp[d];
  float state = 0.f;
  const float* drow = delta + (size_t)b * LSEQ * DINNER + d;
  const float* urow = u + (size_t)b * LSEQ * DINNER + d;
  const float* xd = xdbl + (size_t)b * LSEQ * 96;
  const float* zrow = xz + (size_t)b * LSEQ * (2 * DINNER) + DINNER + d;
  float* yrow = y + (size_t)b * LSEQ * DINNER + d;
  for (int l = 0; l < LSEQ; l++) {
    float dt = drow[(size_t)l * DINNER];
    float uu = urow[(size_t)l * DINNER];
    float Bv = xd[l * 96 + 64 + s];
    float Cv = xd[l * 96 + 80 + s];
    float dA = __expf(dt * Aval);
    state = fmaf(dA, state, dt * uu * Bv);
    float p = state * Cv;
    p += __shfl_xor(p, 1);
    p += __shfl_xor(p, 2);
    p += __shfl_xor(p, 4);
    p += __shfl_xor(p, 8);
    if (s == 0) {
      float zz = zrow[(size_t)l * (2 * DINNER)];
      float yv = (p + uu * Dval) * (zz / (1.f + __expf(-zz)));
      yrow[(size_t)l * DINNER] = yv;
    }
  }
}

extern "C" void kernel_launch(void* const* d_in, const int* in_sizes, int n_in,
                              void* d_out, int out_size, void* d_ws, size_t ws_size,
                              hipStream_t stream) {
  const float* hidden    = (const float*)d_in[0];
  const float* norm_w    = (const float*)d_in[1];
  const float* norm_b    = (const float*)d_in[2];
  const float* in_proj_w = (const float*)d_in[3];
  const float* conv_w    = (const float*)d_in[4];
  const float* conv_b    = (const float*)d_in[5];
  const float* x_proj_w  = (const float*)d_in[6];
  const float* dt_proj_w = (const float*)d_in[7];
  const float* dt_proj_b = (const float*)d_in[8];
  const float* A_log     = (const float*)d_in[9];
  const float* Dp        = (const float*)d_in[10];
  const float* out_proj_w= (const float*)d_in[11];
  const float* fnw       = (const float*)d_in[12];
  const float* fnb       = (const float*)d_in[13];
  float* out = (float*)d_out;

  float* residual = (float*)d_ws;                        // ROWS*DMODEL
  float* h        = residual + (size_t)ROWS * DMODEL;    // ROWS*DMODEL
  float* xz       = h + (size_t)ROWS * DMODEL;           // ROWS*2*DINNER
  float* xbuf     = xz + (size_t)ROWS * 2 * DINNER;      // ROWS*DINNER
  float* delta    = xbuf + (size_t)ROWS * DINNER;        // ROWS*DINNER
  float* ybuf     = delta + (size_t)ROWS * DINNER;       // ROWS*DINNER
  float* xdbl     = ybuf + (size_t)ROWS * DINNER;        // ROWS*96

  for (int i = 0; i < N_LAYERS; i++) {
    // LN (layer 0 also copies hidden -> residual)
    ln_kernel<<<ROWS, 256, 0, stream>>>(
        i == 0 ? hidden : residual, i == 0 ? residual : nullptr,
        norm_w + (size_t)i * DMODEL, norm_b + (size_t)i * DMODEL, h);
    // in_proj: [4096,1024] @ [4096,1024]^T -> xz [4096,4096]
    {
      dim3 g(2 * DINNER / 64, ROWS / 64);
      gemm_kernel<0, false, false><<<g, 256, 0, stream>>>(
          h, DMODEL, in_proj_w + (size_t)i * 2 * DINNER * DMODEL,
          xz, 2 * DINNER, 2 * DINNER, DMODEL, nullptr, nullptr, 0);
    }
    // conv1d + silu
    conv_silu_kernel<<<(size_t)ROWS * DINNER / 4 / 256, 256, 0, stream>>>(
        xz, conv_w + (size_t)i * DINNER * DCONV, conv_b + (size_t)i * DINNER, xbuf);
    // x_proj: [4096,2048] @ [96,2048]^T -> xdbl [4096,96]
    {
      dim3 g(2, ROWS / 64);
      gemm_kernel<0, false, false><<<g, 256, 0, stream>>>(
          xbuf, DINNER, x_proj_w + (size_t)i * 96 * DINNER,
          xdbl, 96, 96, DINNER, nullptr, nullptr, 0);
    }
    // dt_proj + bias + softplus: [4096,64] @ [2048,64]^T -> delta [4096,2048]
    {
      dim3 g(DINNER / 64, ROWS / 64);
      gemm_kernel<1, false, true><<<g, 256, 0, stream>>>(
          xdbl, 96, dt_proj_w + (size_t)i * DINNER * DTRANK,
          delta, DINNER, DINNER, DTRANK, dt_proj_b + (size_t)i * DINNER, nullptr, 0);
    }
    // selective scan + gating epilogue
    scan_kernel<<<65536 / 256, 256, 0, stream>>>(
        delta, xbuf, xdbl, xz, A_log + (size_t)i * DINNER * DSTATE,
        Dp + (size_t)i * DINNER, ybuf);
    // out_proj (+ residual accumulate): [4096,2048] @ [1024,2048]^T -> residual
    {
      dim3 g(DMODEL / 64, ROWS / 64);
      gemm_kernel<0, true, false><<<g, 256, 0, stream>>>(
          ybuf, DINNER, out_proj_w + (size_t)i * DMODEL * DINNER,
          residual, DMODEL, DMODEL, DINNER, nullptr, residual, DMODEL);
    }
  }
  ln_kernel<<<ROWS, 256, 0, stream>>>(residual, nullptr, fnw, fnb, out);
}

// Round 2
// 5153.923 us; speedup vs baseline: 2.0390x; 2.0390x over previous
//
#include <hip/hip_runtime.h>
#include <math.h>

#define N_LAYERS 4
#define DMODEL 1024
#define DINNER 2048
#define DSTATE 16
#define DTRANK 64
#define DCONV 4
#define NBATCH 2
#define LSEQ 2048
#define LNEPS 1e-5f
#define ROWS (NBATCH * LSEQ)   // 4096
#define CLEN 32
#define NCHUNK (LSEQ / CLEN)   // 64

// ---------------- LayerNorm (row per block, 1024 cols, 256 threads) ----------
__global__ __launch_bounds__(256) void ln_kernel(
    const float* __restrict__ src, float* __restrict__ res_copy,
    const float* __restrict__ w, const float* __restrict__ b,
    float* __restrict__ out) {
  int row = blockIdx.x;
  int t = threadIdx.x;
  const float4* srow = (const float4*)(src + (size_t)row * DMODEL);
  float4 v = srow[t];
  if (res_copy) ((float4*)(res_copy + (size_t)row * DMODEL))[t] = v;
  float s = v.x + v.y + v.z + v.w;
  float sq = v.x * v.x + v.y * v.y + v.z * v.z + v.w * v.w;
  #pragma unroll
  for (int o = 32; o >= 1; o >>= 1) {
    s += __shfl_xor(s, o);
    sq += __shfl_xor(sq, o);
  }
  __shared__ float ss[4], ssq[4];
  int wid = t >> 6, lane = t & 63;
  if (lane == 0) { ss[wid] = s; ssq[wid] = sq; }
  __syncthreads();
  s = ss[0] + ss[1] + ss[2] + ss[3];
  sq = ssq[0] + ssq[1] + ssq[2] + ssq[3];
  float mu = s * (1.f / DMODEL);
  float var = sq * (1.f / DMODEL) - mu * mu;
  float rs = rsqrtf(var + LNEPS);
  float4 wv = ((const float4*)w)[t];
  float4 bv = ((const float4*)b)[t];
  float4 o4;
  o4.x = (v.x - mu) * rs * wv.x + bv.x;
  o4.y = (v.y - mu) * rs * wv.y + bv.y;
  o4.z = (v.z - mu) * rs * wv.z + bv.z;
  o4.w = (v.w - mu) * rs * wv.w + bv.w;
  ((float4*)(out + (size_t)row * DMODEL))[t] = o4;
}

__device__ __forceinline__ float softplus_f(float x) {
  return x > 20.f ? x : log1pf(expf(x));
}

// ---------------- Generic fp32 GEMM: C[M,N] = act(A[M,K] @ W[N,K]^T + bias) (+add)
template<int ACT, bool ADD, bool BIAS>
__global__ __launch_bounds__(256) void gemm_kernel(
    const float* __restrict__ A, int lda,
    const float* __restrict__ W,          // [N, K] row-major
    float* __restrict__ C, int ldc,
    int N, int K,
    const float* __restrict__ bias,
    const float* __restrict__ addsrc, int ldadd) {
  __shared__ float As[16][68];
  __shared__ float Ws[16][68];
  int t = threadIdx.x;
  int tx = t & 15, ty = t >> 4;
  int m0 = blockIdx.y * 64, n0 = blockIdx.x * 64;
  int lk = t & 15;
  int lrow = t >> 4;
  float acc[4][4] = {{0.f}};
  for (int k0 = 0; k0 < K; k0 += 16) {
    #pragma unroll
    for (int i = 0; i < 4; i++) {
      int r = lrow + i * 16;
      As[lk][r] = A[(size_t)(m0 + r) * lda + k0 + lk];
    }
    #pragma unroll
    for (int i = 0; i < 4; i++) {
      int r = lrow + i * 16;
      int n = n0 + r;
      Ws[lk][r] = (n < N) ? W[(size_t)n * K + k0 + lk] : 0.f;
    }
    __syncthreads();
    #pragma unroll
    for (int kk = 0; kk < 16; kk++) {
      float4 av = *(const float4*)&As[kk][ty * 4];
      float4 bv = *(const float4*)&Ws[kk][tx * 4];
      float a[4] = {av.x, av.y, av.z, av.w};
      float bb[4] = {bv.x, bv.y, bv.z, bv.w};
      #pragma unroll
      for (int i = 0; i < 4; i++)
        #pragma unroll
        for (int j = 0; j < 4; j++)
          acc[i][j] = fmaf(a[i], bb[j], acc[i][j]);
    }
    __syncthreads();
  }
  #pragma unroll
  for (int i = 0; i < 4; i++) {
    int m = m0 + ty * 4 + i;
    #pragma unroll
    for (int j = 0; j < 4; j++) {
      int n = n0 + tx * 4 + j;
      if (n < N) {
        float vv = acc[i][j];
        if (BIAS) vv += bias[n];
        if (ACT == 1) vv = softplus_f(vv);
        if (ADD) vv += addsrc[(size_t)m * ldadd + n];
        C[(size_t)m * ldc + n] = vv;
      }
    }
  }
}

// ---------------- causal depthwise conv1d + SiLU -----------------------------
__global__ __launch_bounds__(256) void conv_silu_kernel(
    const float* __restrict__ xz, const float* __restrict__ cw,
    const float* __restrict__ cb, float* __restrict__ x) {
  int tid = blockIdx.x * 256 + threadIdx.x;
  int dv = tid & (DINNER / 4 - 1);
  int row = tid / (DINNER / 4);
  int l = row & (LSEQ - 1);
  int d = dv * 4;
  float acc0 = cb[d], acc1 = cb[d + 1], acc2 = cb[d + 2], acc3 = cb[d + 3];
  #pragma unroll
  for (int k = 0; k < DCONV; k++) {
    int ll = l - (DCONV - 1) + k;
    if (ll >= 0) {
      const float4 xv = *(const float4*)(xz + (size_t)(row - (DCONV - 1) + k) * (2 * DINNER) + d);
      acc0 = fmaf(xv.x, cw[(d + 0) * DCONV + k], acc0);
      acc1 = fmaf(xv.y, cw[(d + 1) * DCONV + k], acc1);
      acc2 = fmaf(xv.z, cw[(d + 2) * DCONV + k], acc2);
      acc3 = fmaf(xv.w, cw[(d + 3) * DCONV + k], acc3);
    }
  }
  float4 o;
  o.x = acc0 / (1.f + __expf(-acc0));
  o.y = acc1 / (1.f + __expf(-acc1));
  o.z = acc2 / (1.f + __expf(-acc2));
  o.w = acc3 / (1.f + __expf(-acc3));
  *(float4*)(x + (size_t)row * DINNER + d) = o;
}

// ================= chunk-parallel selective scan ============================
// P1: thread per (b, chunk, d); 16 states in regs; 32 steps.
// Writes per-chunk carry (Aprod[16], state[16]) at [b][chunk][d][s] = tid*16+s.
__global__ __launch_bounds__(256, 4) void scan_p1(
    const float* __restrict__ delta, const float* __restrict__ u,
    const float* __restrict__ xdbl, const float* __restrict__ A_log,
    float* __restrict__ aprodbuf, float* __restrict__ statebuf) {
  int tid = blockIdx.x * 256 + threadIdx.x;   // B*NCHUNK*DINNER = 262144
  int d = tid & (DINNER - 1);
  int chunk = (tid >> 11) & (NCHUNK - 1);
  int b = tid >> 17;
  float A[DSTATE], st[DSTATE], ap[DSTATE];
  #pragma unroll
  for (int s = 0; s < DSTATE; s++) {
    A[s] = -__expf(A_log[d * DSTATE + s]);
    st[s] = 0.f;
    ap[s] = 1.f;
  }
  int l0 = chunk * CLEN;
  const float* dptr = delta + ((size_t)b * LSEQ + l0) * DINNER + d;
  const float* uptr = u + ((size_t)b * LSEQ + l0) * DINNER + d;
  const float* xd = xdbl + ((size_t)b * LSEQ + l0) * 96;
  #pragma unroll 4
  for (int l = 0; l < CLEN; l++) {
    float dt = dptr[(size_t)l * DINNER];
    float uu = uptr[(size_t)l * DINNER];
    float du = dt * uu;
    #pragma unroll
    for (int s = 0; s < DSTATE; s++) {
      float dA = __expf(dt * A[s]);
      float Bv = xd[l * 96 + 64 + s];
      st[s] = fmaf(dA, st[s], du * Bv);
      ap[s] *= dA;
    }
  }
  float4* apo = (float4*)(aprodbuf + (size_t)tid * DSTATE);
  float4* sto = (float4*)(statebuf + (size_t)tid * DSTATE);
  #pragma unroll
  for (int q = 0; q < 4; q++) {
    apo[q] = make_float4(ap[4 * q], ap[4 * q + 1], ap[4 * q + 2], ap[4 * q + 3]);
    sto[q] = make_float4(st[4 * q], st[4 * q + 1], st[4 * q + 2], st[4 * q + 3]);
  }
}

// P2: thread per (b,d,s); sequential combine over 64 chunks; writes carry-in.
__global__ __launch_bounds__(256) void scan_p2(
    const float* __restrict__ aprodbuf, const float* __restrict__ statebuf,
    float* __restrict__ carryin) {
  int tid = blockIdx.x * 256 + threadIdx.x;   // B*DINNER*DSTATE = 65536
  int ds = tid & (DINNER * DSTATE - 1);
  int b = tid >> 15;
  float carry = 0.f;
  size_t base = (size_t)b * NCHUNK * DINNER * DSTATE + ds;
  for (int c = 0; c < NCHUNK; c++) {
    size_t idx = base + (size_t)c * (DINNER * DSTATE);
    carryin[idx] = carry;
    carry = fmaf(aprodbuf[idx], carry, statebuf[idx]);
  }
}

// P3: same decomposition as P1, seeded with carry-in; computes gated y.
__global__ __launch_bounds__(256, 4) void scan_p3(
    const float* __restrict__ delta, const float* __restrict__ u,
    const float* __restrict__ xdbl, const float* __restrict__ xz,
    const float* __restrict__ A_log, const float* __restrict__ Dp,
    const float* __restrict__ carryin, float* __restrict__ y) {
  int tid = blockIdx.x * 256 + threadIdx.x;
  int d = tid & (DINNER - 1);
  int chunk = (tid >> 11) & (NCHUNK - 1);
  int b = tid >> 17;
  float A[DSTATE], st[DSTATE];
  const float4* ci = (const float4*)(carryin + (size_t)tid * DSTATE);
  #pragma unroll
  for (int q = 0; q < 4; q++) {
    float4 cv = ci[q];
    st[4 * q] = cv.x; st[4 * q + 1] = cv.y; st[4 * q + 2] = cv.z; st[4 * q + 3] = cv.w;
  }
  #pragma unroll
  for (int s = 0; s < DSTATE; s++) A[s] = -__expf(A_log[d * DSTATE + s]);
  float Dval = Dp[d];
  int l0 = chunk * CLEN;
  const float* dptr = delta + ((size_t)b * LSEQ + l0) * DINNER + d;
  const float* uptr = u + ((size_t)b * LSEQ + l0) * DINNER + d;
  const float* xd = xdbl + ((size_t)b * LSEQ + l0) * 96;
  const float* zptr = xz + ((size_t)b * LSEQ + l0) * (2 * DINNER) + DINNER + d;
  float* yptr = y + ((size_t)b * LSEQ + l0) * DINNER + d;
  #pragma unroll 4
  for (int l = 0; l < CLEN; l++) {
    float dt = dptr[(size_t)l * DINNER];
    float uu = uptr[(size_t)l * DINNER];
    float du = dt * uu;
    float acc = 0.f;
    #pragma unroll
    for (int s = 0; s < DSTATE; s++) {
      float dA = __expf(dt * A[s]);
      float Bv = xd[l * 96 + 64 + s];
      float Cv = xd[l * 96 + 80 + s];
      st[s] = fmaf(dA, st[s], du * Bv);
      acc = fmaf(st[s], Cv, acc);
    }
    float zz = zptr[(size_t)l * (2 * DINNER)];
    float yv = (acc + uu * Dval) * (zz / (1.f + __expf(-zz)));
    yptr[(size_t)l * DINNER] = yv;
  }
}

extern "C" void kernel_launch(void* const* d_in, const int* in_sizes, int n_in,
                              void* d_out, int out_size, void* d_ws, size_t ws_size,
                              hipStream_t stream) {
  const float* hidden    = (const float*)d_in[0];
  const float* norm_w    = (const float*)d_in[1];
  const float* norm_b    = (const float*)d_in[2];
  const float* in_proj_w = (const float*)d_in[3];
  const float* conv_w    = (const float*)d_in[4];
  const float* conv_b    = (const float*)d_in[5];
  const float* x_proj_w  = (const float*)d_in[6];
  const float* dt_proj_w = (const float*)d_in[7];
  const float* dt_proj_b = (const float*)d_in[8];
  const float* A_log     = (const float*)d_in[9];
  const float* Dp        = (const float*)d_in[10];
  const float* out_proj_w= (const float*)d_in[11];
  const float* fnw       = (const float*)d_in[12];
  const float* fnb       = (const float*)d_in[13];
  float* out = (float*)d_out;

  float* residual = (float*)d_ws;                        // 4M f
  float* h        = residual + (size_t)ROWS * DMODEL;    // 4M f
  float* xz       = h + (size_t)ROWS * DMODEL;           // 16M f
  float* xbuf     = xz + (size_t)ROWS * 2 * DINNER;      // 8M f
  float* delta    = xbuf + (size_t)ROWS * DINNER;        // 8M f
  float* ybuf     = delta + (size_t)ROWS * DINNER;       // 8M f
  float* xdbl     = ybuf + (size_t)ROWS * DINNER;        // 0.375M f
  float* carryin  = xdbl + (size_t)ROWS * 96;            // 4M f
  // P1 carry buffers overlay ybuf (dead until P3 writes it, consumed by P2)
  float* aprodbuf = ybuf;                                // 4M f
  float* statebuf = ybuf + (size_t)NBATCH * NCHUNK * DINNER * DSTATE;

  for (int i = 0; i < N_LAYERS; i++) {
    ln_kernel<<<ROWS, 256, 0, stream>>>(
        i == 0 ? hidden : residual, i == 0 ? residual : nullptr,
        norm_w + (size_t)i * DMODEL, norm_b + (size_t)i * DMODEL, h);
    {
      dim3 g(2 * DINNER / 64, ROWS / 64);
      gemm_kernel<0, false, false><<<g, 256, 0, stream>>>(
          h, DMODEL, in_proj_w + (size_t)i * 2 * DINNER * DMODEL,
          xz, 2 * DINNER, 2 * DINNER, DMODEL, nullptr, nullptr, 0);
    }
    conv_silu_kernel<<<(size_t)ROWS * DINNER / 4 / 256, 256, 0, stream>>>(
        xz, conv_w + (size_t)i * DINNER * DCONV, conv_b + (size_t)i * DINNER, xbuf);
    {
      dim3 g(2, ROWS / 64);
      gemm_kernel<0, false, false><<<g, 256, 0, stream>>>(
          xbuf, DINNER, x_proj_w + (size_t)i * 96 * DINNER,
          xdbl, 96, 96, DINNER, nullptr, nullptr, 0);
    }
    {
      dim3 g(DINNER / 64, ROWS / 64);
      gemm_kernel<1, false, true><<<g, 256, 0, stream>>>(
          xdbl, 96, dt_proj_w + (size_t)i * DINNER * DTRANK,
          delta, DINNER, DINNER, DTRANK, dt_proj_b + (size_t)i * DINNER, nullptr, 0);
    }
    // chunk-parallel scan
    scan_p1<<<NBATCH * NCHUNK * DINNER / 256, 256, 0, stream>>>(
        delta, xbuf, xdbl, A_log + (size_t)i * DINNER * DSTATE, aprodbuf, statebuf);
    scan_p2<<<NBATCH * DINNER * DSTATE / 256, 256, 0, stream>>>(
        aprodbuf, statebuf, carryin);
    scan_p3<<<NBATCH * NCHUNK * DINNER / 256, 256, 0, stream>>>(
        delta, xbuf, xdbl, xz, A_log + (size_t)i * DINNER * DSTATE,
        Dp + (size_t)i * DINNER, carryin, ybuf);
    {
      dim3 g(DMODEL / 64, ROWS / 64);
      gemm_kernel<0, true, false><<<g, 256, 0, stream>>>(
          ybuf, DINNER, out_proj_w + (size_t)i * DMODEL * DINNER,
          residual, DMODEL, DMODEL, DINNER, nullptr, residual, DMODEL);
    }
  }
  ln_kernel<<<ROWS, 256, 0, stream>>>(residual, nullptr, fnw, fnb, out);
}

// Round 4
// 1750.436 us; speedup vs baseline: 6.0036x; 2.9444x over previous
//
#include <hip/hip_runtime.h>
#include <math.h>

#define N_LAYERS 4
#define DMODEL 1024
#define DINNER 2048
#define DSTATE 16
#define DTRANK 64
#define DCONV 4
#define NBATCH 2
#define LSEQ 2048
#define LNEPS 1e-5f
#define ROWS (NBATCH * LSEQ)   // 4096
#define CLEN 32
#define NCHUNK (LSEQ / CLEN)   // 64
#define XP 128                 // padded x_proj output pitch (dt 0:64, B 64:80, C 80:96)

typedef __attribute__((ext_vector_type(8))) short bf16x8;
typedef __attribute__((ext_vector_type(4))) float f32x4;

__device__ __forceinline__ unsigned short f2bf(float f) {
  unsigned int u = __float_as_uint(f);
  return (unsigned short)((u + 0x7FFFu + ((u >> 16) & 1u)) >> 16);  // RNE
}
__device__ __forceinline__ float bf2f(unsigned short h) {
  return __uint_as_float(((unsigned int)h) << 16);
}

__device__ __forceinline__ void gload16(const unsigned short* g, unsigned short* l) {
  __builtin_amdgcn_global_load_lds(
      (const __attribute__((address_space(1))) unsigned int*)g,
      (__attribute__((address_space(3))) unsigned int*)l, 16, 0, 0);
}

// ---------------- fp32 -> bf16 weight conversion -----------------------------
__global__ __launch_bounds__(256) void cvt_f2bf(const float* __restrict__ src,
                                                unsigned short* __restrict__ dst, int n4) {
  int i = blockIdx.x * 256 + threadIdx.x;
  if (i >= n4) return;
  float4 v = ((const float4*)src)[i];
  ushort4 o;
  o.x = f2bf(v.x); o.y = f2bf(v.y); o.z = f2bf(v.z); o.w = f2bf(v.w);
  ((ushort4*)dst)[i] = o;
}

// x_proj_w [4][96][2048] -> padded bf16 [4][128][2048] (rows 96..127 zero)
__global__ __launch_bounds__(256) void cvt_xpw(const float* __restrict__ src,
                                               unsigned short* __restrict__ dst) {
  int i = blockIdx.x * 256 + threadIdx.x;    // over 4*128*512
  int col4 = i & 511;
  int row = (i >> 9) & 127;
  int layer = i >> 16;
  float4 v = make_float4(0.f, 0.f, 0.f, 0.f);
  if (row < 96) v = ((const float4*)(src + ((size_t)layer * 96 + row) * 2048))[col4];
  ushort4 o;
  o.x = f2bf(v.x); o.y = f2bf(v.y); o.z = f2bf(v.z); o.w = f2bf(v.w);
  ((ushort4*)(dst + ((size_t)layer * 128 + row) * 2048))[col4] = o;
}

// ---------------- LayerNorm: fp32 in, bf16 (hidden path) or fp32 (final) out -
template<bool OBF>
__global__ __launch_bounds__(256) void ln_kernel(
    const float* __restrict__ src, float* __restrict__ res_copy,
    const float* __restrict__ w, const float* __restrict__ b, void* out) {
  int row = blockIdx.x;
  int t = threadIdx.x;
  const float4* srow = (const float4*)(src + (size_t)row * DMODEL);
  float4 v = srow[t];
  if (res_copy) ((float4*)(res_copy + (size_t)row * DMODEL))[t] = v;
  float s = v.x + v.y + v.z + v.w;
  float sq = v.x * v.x + v.y * v.y + v.z * v.z + v.w * v.w;
  #pragma unroll
  for (int o = 32; o >= 1; o >>= 1) {
    s += __shfl_xor(s, o);
    sq += __shfl_xor(sq, o);
  }
  __shared__ float ss[4], ssq[4];
  int wid = t >> 6, lane = t & 63;
  if (lane == 0) { ss[wid] = s; ssq[wid] = sq; }
  __syncthreads();
  s = ss[0] + ss[1] + ss[2] + ss[3];
  sq = ssq[0] + ssq[1] + ssq[2] + ssq[3];
  float mu = s * (1.f / DMODEL);
  float var = sq * (1.f / DMODEL) - mu * mu;
  float rs = rsqrtf(var + LNEPS);
  float4 wv = ((const float4*)w)[t];
  float4 bv = ((const float4*)b)[t];
  float4 o4;
  o4.x = (v.x - mu) * rs * wv.x + bv.x;
  o4.y = (v.y - mu) * rs * wv.y + bv.y;
  o4.z = (v.z - mu) * rs * wv.z + bv.z;
  o4.w = (v.w - mu) * rs * wv.w + bv.w;
  if (OBF) {
    ushort4 ob;
    ob.x = f2bf(o4.x); ob.y = f2bf(o4.y); ob.z = f2bf(o4.z); ob.w = f2bf(o4.w);
    ((ushort4*)((unsigned short*)out + (size_t)row * DMODEL))[t] = ob;
  } else {
    ((float4*)((float*)out + (size_t)row * DMODEL))[t] = o4;
  }
}

__device__ __forceinline__ float softplus_f(float x) {
  return x > 20.f ? x : log1pf(expf(x));
}

// ---------------- bf16 MFMA GEMM: act(A[M,K] @ W[N,K]^T [+bias]) [+add] ------
// 128x128 tile, 4 waves, BK=32, global_load_lds staging (m97 structure).
// Writes fp32 C (WF32) and/or bf16 Cb (WBF), both at pitch ldc.
template<int ACT, bool BIAS, bool ADD, bool WF32, bool WBF>
__global__ __launch_bounds__(256) void gemm_bf16(
    const unsigned short* __restrict__ A, int lda,
    const unsigned short* __restrict__ W, int ldw,
    float* __restrict__ C, int ldc, int K,
    const float* __restrict__ bias,
    const float* __restrict__ addsrc,
    unsigned short* __restrict__ Cb) {
  __shared__ unsigned short As[128][32];
  __shared__ unsigned short Ws[128][32];
  int t = threadIdx.x;
  int lane = t & 63, wave = t >> 6;
  int wr = wave >> 1, wc = wave & 1;
  int m0 = blockIdx.y * 128, n0 = blockIdx.x * 128;

  int r0 = t >> 2;               // 0..63
  int kk8 = (t & 3) << 3;        // 0,8,16,24
  const unsigned short* Ag  = A + (size_t)(m0 + r0) * lda + kk8;
  const unsigned short* Ag2 = Ag + (size_t)64 * lda;
  const unsigned short* Wg  = W + (size_t)(n0 + r0) * ldw + kk8;
  const unsigned short* Wg2 = Wg + (size_t)64 * ldw;
  unsigned short* la  = &As[r0][kk8];
  unsigned short* la2 = &As[r0 + 64][kk8];
  unsigned short* lw  = &Ws[r0][kk8];
  unsigned short* lw2 = &Ws[r0 + 64][kk8];

  f32x4 zero = {0.f, 0.f, 0.f, 0.f};
  f32x4 acc[4][4];
  #pragma unroll
  for (int m = 0; m < 4; m++)
    #pragma unroll
    for (int n = 0; n < 4; n++) acc[m][n] = zero;

  int frow = lane & 15;
  int fk = (lane >> 4) << 3;

  for (int k0 = 0; k0 < K; k0 += 32) {
    gload16(Ag + k0, la);
    gload16(Ag2 + k0, la2);
    gload16(Wg + k0, lw);
    gload16(Wg2 + k0, lw2);
    __syncthreads();
    bf16x8 af[4], bw[4];
    #pragma unroll
    for (int m = 0; m < 4; m++)
      af[m] = *(const bf16x8*)&As[wr * 64 + m * 16 + frow][fk];
    #pragma unroll
    for (int n = 0; n < 4; n++)
      bw[n] = *(const bf16x8*)&Ws[wc * 64 + n * 16 + frow][fk];
    #pragma unroll
    for (int m = 0; m < 4; m++)
      #pragma unroll
      for (int n = 0; n < 4; n++)
        acc[m][n] = __builtin_amdgcn_mfma_f32_16x16x32_bf16(af[m], bw[n], acc[m][n], 0, 0, 0);
    __syncthreads();
  }

  #pragma unroll
  for (int m = 0; m < 4; m++) {
    int rbase = m0 + wr * 64 + m * 16 + ((lane >> 4) << 2);
    #pragma unroll
    for (int n = 0; n < 4; n++) {
      int ccol = n0 + wc * 64 + n * 16 + (lane & 15);
      #pragma unroll
      for (int j = 0; j < 4; j++) {
        int crow = rbase + j;
        float v = acc[m][n][j];
        if (BIAS) v += bias[ccol];
        if (ACT == 1) v = softplus_f(v);
        if (ADD) v += addsrc[(size_t)crow * ldc + ccol];
        if (WF32) C[(size_t)crow * ldc + ccol] = v;
        if (WBF) Cb[(size_t)crow * ldc + ccol] = f2bf(v);
      }
    }
  }
}

// ---------------- causal depthwise conv1d + SiLU (bf16 in, fp32+bf16 out) ----
__global__ __launch_bounds__(256) void conv_silu_kernel(
    const unsigned short* __restrict__ xz, const float* __restrict__ cw,
    const float* __restrict__ cb, float* __restrict__ x,
    unsigned short* __restrict__ xbf) {
  int tid = blockIdx.x * 256 + threadIdx.x;
  int dv = tid & (DINNER / 4 - 1);
  int row = tid / (DINNER / 4);
  int l = row & (LSEQ - 1);
  int d = dv * 4;
  float acc0 = cb[d], acc1 = cb[d + 1], acc2 = cb[d + 2], acc3 = cb[d + 3];
  #pragma unroll
  for (int k = 0; k < DCONV; k++) {
    int ll = l - (DCONV - 1) + k;
    if (ll >= 0) {
      const ushort4 xv = *(const ushort4*)(xz + (size_t)(row - (DCONV - 1) + k) * (2 * DINNER) + d);
      acc0 = fmaf(bf2f(xv.x), cw[(d + 0) * DCONV + k], acc0);
      acc1 = fmaf(bf2f(xv.y), cw[(d + 1) * DCONV + k], acc1);
      acc2 = fmaf(bf2f(xv.z), cw[(d + 2) * DCONV + k], acc2);
      acc3 = fmaf(bf2f(xv.w), cw[(d + 3) * DCONV + k], acc3);
    }
  }
  float4 o;
  o.x = acc0 / (1.f + __expf(-acc0));
  o.y = acc1 / (1.f + __expf(-acc1));
  o.z = acc2 / (1.f + __expf(-acc2));
  o.w = acc3 / (1.f + __expf(-acc3));
  *(float4*)(x + (size_t)row * DINNER + d) = o;
  ushort4 ob;
  ob.x = f2bf(o.x); ob.y = f2bf(o.y); ob.z = f2bf(o.z); ob.w = f2bf(o.w);
  *(ushort4*)(xbf + (size_t)row * DINNER + d) = ob;
}

// ================= chunk-parallel selective scan ============================
__global__ __launch_bounds__(256, 4) void scan_p1(
    const float* __restrict__ delta, const float* __restrict__ u,
    const float* __restrict__ xdbl, const float* __restrict__ A_log,
    float* __restrict__ aprodbuf, float* __restrict__ statebuf) {
  int tid = blockIdx.x * 256 + threadIdx.x;   // B*NCHUNK*DINNER = 262144
  int d = tid & (DINNER - 1);
  int chunk = (tid >> 11) & (NCHUNK - 1);
  int b = tid >> 17;
  float A[DSTATE], st[DSTATE], ap[DSTATE];
  #pragma unroll
  for (int s = 0; s < DSTATE; s++) {
    A[s] = -__expf(A_log[d * DSTATE + s]);
    st[s] = 0.f;
    ap[s] = 1.f;
  }
  int l0 = chunk * CLEN;
  const float* dptr = delta + ((size_t)b * LSEQ + l0) * DINNER + d;
  const float* uptr = u + ((size_t)b * LSEQ + l0) * DINNER + d;
  const float* xd = xdbl + ((size_t)b * LSEQ + l0) * XP;
  #pragma unroll 4
  for (int l = 0; l < CLEN; l++) {
    float dt = dptr[(size_t)l * DINNER];
    float uu = uptr[(size_t)l * DINNER];
    float du = dt * uu;
    #pragma unroll
    for (int s = 0; s < DSTATE; s++) {
      float dA = __expf(dt * A[s]);
      float Bv = xd[l * XP + 64 + s];
      st[s] = fmaf(dA, st[s], du * Bv);
      ap[s] *= dA;
    }
  }
  float4* apo = (float4*)(aprodbuf + (size_t)tid * DSTATE);
  float4* sto = (float4*)(statebuf + (size_t)tid * DSTATE);
  #pragma unroll
  for (int q = 0; q < 4; q++) {
    apo[q] = make_float4(ap[4 * q], ap[4 * q + 1], ap[4 * q + 2], ap[4 * q + 3]);
    sto[q] = make_float4(st[4 * q], st[4 * q + 1], st[4 * q + 2], st[4 * q + 3]);
  }
}

__global__ __launch_bounds__(256) void scan_p2(
    const float* __restrict__ aprodbuf, const float* __restrict__ statebuf,
    float* __restrict__ carryin) {
  int tid = blockIdx.x * 256 + threadIdx.x;   // B*DINNER*DSTATE = 65536
  int ds = tid & (DINNER * DSTATE - 1);
  int b = tid >> 15;
  float carry = 0.f;
  size_t base = (size_t)b * NCHUNK * DINNER * DSTATE + ds;
  for (int c = 0; c < NCHUNK; c++) {
    size_t idx = base + (size_t)c * (DINNER * DSTATE);
    carryin[idx] = carry;
    carry = fmaf(aprodbuf[idx], carry, statebuf[idx]);
  }
}

__global__ __launch_bounds__(256, 4) void scan_p3(
    const float* __restrict__ delta, const float* __restrict__ u,
    const float* __restrict__ xdbl, const unsigned short* __restrict__ xzbf,
    const float* __restrict__ A_log, const float* __restrict__ Dp,
    const float* __restrict__ carryin, unsigned short* __restrict__ ybf) {
  int tid = blockIdx.x * 256 + threadIdx.x;
  int d = tid & (DINNER - 1);
  int chunk = (tid >> 11) & (NCHUNK - 1);
  int b = tid >> 17;
  float A[DSTATE], st[DSTATE];
  const float4* ci = (const float4*)(carryin + (size_t)tid * DSTATE);
  #pragma unroll
  for (int q = 0; q < 4; q++) {
    float4 cv = ci[q];
    st[4 * q] = cv.x; st[4 * q + 1] = cv.y; st[4 * q + 2] = cv.z; st[4 * q + 3] = cv.w;
  }
  #pragma unroll
  for (int s = 0; s < DSTATE; s++) A[s] = -__expf(A_log[d * DSTATE + s]);
  float Dval = Dp[d];
  int l0 = chunk * CLEN;
  const float* dptr = delta + ((size_t)b * LSEQ + l0) * DINNER + d;
  const float* uptr = u + ((size_t)b * LSEQ + l0) * DINNER + d;
  const float* xd = xdbl + ((size_t)b * LSEQ + l0) * XP;
  const unsigned short* zptr = xzbf + ((size_t)b * LSEQ + l0) * (2 * DINNER) + DINNER + d;
  unsigned short* yptr = ybf + ((size_t)b * LSEQ + l0) * DINNER + d;
  #pragma unroll 4
  for (int l = 0; l < CLEN; l++) {
    float dt = dptr[(size_t)l * DINNER];
    float uu = uptr[(size_t)l * DINNER];
    float du = dt * uu;
    float acc = 0.f;
    #pragma unroll
    for (int s = 0; s < DSTATE; s++) {
      float dA = __expf(dt * A[s]);
      float Bv = xd[l * XP + 64 + s];
      float Cv = xd[l * XP + 80 + s];
      st[s] = fmaf(dA, st[s], du * Bv);
      acc = fmaf(st[s], Cv, acc);
    }
    float zz = bf2f(zptr[(size_t)l * (2 * DINNER)]);
    float yv = (acc + uu * Dval) * (zz / (1.f + __expf(-zz)));
    yptr[(size_t)l * DINNER] = f2bf(yv);
  }
}

extern "C" void kernel_launch(void* const* d_in, const int* in_sizes, int n_in,
                              void* d_out, int out_size, void* d_ws, size_t ws_size,
                              hipStream_t stream) {
  const float* hidden    = (const float*)d_in[0];
  const float* norm_w    = (const float*)d_in[1];
  const float* norm_b    = (const float*)d_in[2];
  const float* in_proj_w = (const float*)d_in[3];
  const float* conv_w    = (const float*)d_in[4];
  const float* conv_b    = (const float*)d_in[5];
  const float* x_proj_w  = (const float*)d_in[6];
  const float* dt_proj_w = (const float*)d_in[7];
  const float* dt_proj_b = (const float*)d_in[8];
  const float* A_log     = (const float*)d_in[9];
  const float* Dp        = (const float*)d_in[10];
  const float* out_proj_w= (const float*)d_in[11];
  const float* fnw       = (const float*)d_in[12];
  const float* fnb       = (const float*)d_in[13];
  float* out = (float*)d_out;

  // ---- workspace layout (≈190 MB total; round-2's proven footprint was 209.5 MB)
  float* residual = (float*)d_ws;                                       // 16 MB
  float* xbuf     = residual + (size_t)ROWS * DMODEL;                   // 32 MB
  float* delta    = xbuf + (size_t)ROWS * DINNER;                       // 32 MB
  float* aprod    = delta + (size_t)ROWS * DINNER;                      // 16 MB
  float* statebuf = aprod + (size_t)NBATCH * NCHUNK * DINNER * DSTATE;  // 16 MB
  float* xdbl     = statebuf + (size_t)NBATCH * NCHUNK * DINNER * DSTATE; // 2 MB
  float* fend     = xdbl + (size_t)ROWS * XP;

  unsigned short* xz_bf   = (unsigned short*)fend;                      // 32 MB
  unsigned short* xbuf_bf = xz_bf + (size_t)ROWS * 2 * DINNER;          // 16 MB
  unsigned short* xdbl_bf = xbuf_bf + (size_t)ROWS * DINNER;            // 1 MB
  unsigned short* xpw_bf  = xdbl_bf + (size_t)ROWS * XP;                // 2 MB (all layers)
  unsigned short* dtw_bf  = xpw_bf + (size_t)N_LAYERS * XP * DINNER;    // 1 MB (all layers)
  unsigned short* ipw_bf  = dtw_bf + (size_t)N_LAYERS * DINNER * DTRANK;// 16 MB (per layer)
  unsigned short* opw_bf  = ipw_bf + (size_t)2 * DINNER * DMODEL;       // 8 MB (per layer)

  // overlays (lifetime-disjoint):
  unsigned short* h_bf    = (unsigned short*)statebuf;  // 8 MB in 16 MB; dead before p1 writes
  unsigned short* ybuf_bf = (unsigned short*)aprod;     // 16 MB; written by p3 after p2 reads aprod
  float*          carryin = (float*)xbuf_bf;            // 16 MB; xbuf_bf dead after x_proj

  // one-time small weight conversions
  cvt_xpw<<<N_LAYERS * XP * DINNER / 4 / 256, 256, 0, stream>>>(x_proj_w, xpw_bf);
  {
    int n4 = N_LAYERS * DINNER * DTRANK / 4;
    cvt_f2bf<<<n4 / 256, 256, 0, stream>>>(dt_proj_w, dtw_bf, n4);
  }

  for (int i = 0; i < N_LAYERS; i++) {
    // per-layer big weight conversions
    {
      int n4 = 2 * DINNER * DMODEL / 4;
      cvt_f2bf<<<n4 / 256, 256, 0, stream>>>(
          in_proj_w + (size_t)i * 2 * DINNER * DMODEL, ipw_bf, n4);
      n4 = DMODEL * DINNER / 4;
      cvt_f2bf<<<n4 / 256, 256, 0, stream>>>(
          out_proj_w + (size_t)i * DMODEL * DINNER, opw_bf, n4);
    }
    ln_kernel<true><<<ROWS, 256, 0, stream>>>(
        i == 0 ? hidden : residual, i == 0 ? residual : nullptr,
        norm_w + (size_t)i * DMODEL, norm_b + (size_t)i * DMODEL, h_bf);
    // in_proj -> xz bf16 only
    {
      dim3 g(2 * DINNER / 128, ROWS / 128);
      gemm_bf16<0, false, false, false, true><<<g, 256, 0, stream>>>(
          h_bf, DMODEL, ipw_bf, DMODEL, nullptr, 2 * DINNER, DMODEL,
          nullptr, nullptr, xz_bf);
    }
    conv_silu_kernel<<<(size_t)ROWS * DINNER / 4 / 256, 256, 0, stream>>>(
        xz_bf, conv_w + (size_t)i * DINNER * DCONV, conv_b + (size_t)i * DINNER,
        xbuf, xbuf_bf);
    // x_proj (padded N=128) -> xdbl fp32 + bf16
    {
      dim3 g(1, ROWS / 128);
      gemm_bf16<0, false, false, true, true><<<g, 256, 0, stream>>>(
          xbuf_bf, DINNER, xpw_bf + (size_t)i * XP * DINNER, DINNER,
          xdbl, XP, DINNER, nullptr, nullptr, xdbl_bf);
    }
    // dt_proj + bias + softplus -> delta fp32
    {
      dim3 g(DINNER / 128, ROWS / 128);
      gemm_bf16<1, true, false, true, false><<<g, 256, 0, stream>>>(
          xdbl_bf, XP, dtw_bf + (size_t)i * DINNER * DTRANK, DTRANK,
          delta, DINNER, DTRANK, dt_proj_b + (size_t)i * DINNER,
          nullptr, nullptr);
    }
    // chunk-parallel scan
    scan_p1<<<NBATCH * NCHUNK * DINNER / 256, 256, 0, stream>>>(
        delta, xbuf, xdbl, A_log + (size_t)i * DINNER * DSTATE, aprod, statebuf);
    scan_p2<<<NBATCH * DINNER * DSTATE / 256, 256, 0, stream>>>(
        aprod, statebuf, carryin);
    scan_p3<<<NBATCH * NCHUNK * DINNER / 256, 256, 0, stream>>>(
        delta, xbuf, xdbl, xz_bf, A_log + (size_t)i * DINNER * DSTATE,
        Dp + (size_t)i * DINNER, carryin, ybuf_bf);
    // out_proj + residual -> residual fp32
    {
      dim3 g(DMODEL / 128, ROWS / 128);
      gemm_bf16<0, false, true, true, false><<<g, 256, 0, stream>>>(
          ybuf_bf, DINNER, opw_bf, DINNER,
          residual, DMODEL, DINNER, nullptr, residual, nullptr);
    }
  }
  ln_kernel<false><<<ROWS, 256, 0, stream>>>(residual, nullptr, fnw, fnb, out);
}

// Round 5
// 1669.484 us; speedup vs baseline: 6.2947x; 1.0485x over previous
//
#include <hip/hip_runtime.h>
#include <math.h>

#define N_LAYERS 4
#define DMODEL 1024
#define DINNER 2048
#define DSTATE 16
#define DTRANK 64
#define DCONV 4
#define NBATCH 2
#define LSEQ 2048
#define LNEPS 1e-5f
#define ROWS (NBATCH * LSEQ)   // 4096
#define CLEN 32
#define NCHUNK (LSEQ / CLEN)   // 64
#define XP 128                 // padded x_proj output pitch (dt 0:64, B 64:80, C 80:96)
#define KSLICE 512             // x_proj split-K slice
#define NSLICE (DINNER / KSLICE)

typedef __attribute__((ext_vector_type(8))) short bf16x8;
typedef __attribute__((ext_vector_type(4))) float f32x4;

__device__ __forceinline__ unsigned short f2bf(float f) {
  unsigned int u = __float_as_uint(f);
  return (unsigned short)((u + 0x7FFFu + ((u >> 16) & 1u)) >> 16);  // RNE
}
__device__ __forceinline__ float bf2f(unsigned short h) {
  return __uint_as_float(((unsigned int)h) << 16);
}

__device__ __forceinline__ void gload16(const unsigned short* g, unsigned short* l) {
  __builtin_amdgcn_global_load_lds(
      (const __attribute__((address_space(1))) unsigned int*)g,
      (__attribute__((address_space(3))) unsigned int*)l, 16, 0, 0);
}

// ---------------- fp32 -> bf16 weight conversion -----------------------------
__global__ __launch_bounds__(256) void cvt_f2bf(const float* __restrict__ src,
                                                unsigned short* __restrict__ dst, int n4) {
  int i = blockIdx.x * 256 + threadIdx.x;
  if (i >= n4) return;
  float4 v = ((const float4*)src)[i];
  ushort4 o;
  o.x = f2bf(v.x); o.y = f2bf(v.y); o.z = f2bf(v.z); o.w = f2bf(v.w);
  ((ushort4*)dst)[i] = o;
}

// x_proj_w [4][96][2048] -> padded bf16 [4][128][2048] (rows 96..127 zero)
__global__ __launch_bounds__(256) void cvt_xpw(const float* __restrict__ src,
                                               unsigned short* __restrict__ dst) {
  int i = blockIdx.x * 256 + threadIdx.x;    // over 4*128*512
  int col4 = i & 511;
  int row = (i >> 9) & 127;
  int layer = i >> 16;
  float4 v = make_float4(0.f, 0.f, 0.f, 0.f);
  if (row < 96) v = ((const float4*)(src + ((size_t)layer * 96 + row) * 2048))[col4];
  ushort4 o;
  o.x = f2bf(v.x); o.y = f2bf(v.y); o.z = f2bf(v.z); o.w = f2bf(v.w);
  ((ushort4*)(dst + ((size_t)layer * 128 + row) * 2048))[col4] = o;
}

// ---------------- LayerNorm: fp32 in, bf16 (hidden path) or fp32 (final) out -
template<bool OBF>
__global__ __launch_bounds__(256) void ln_kernel(
    const float* __restrict__ src, float* __restrict__ res_copy,
    const float* __restrict__ w, const float* __restrict__ b, void* out) {
  int row = blockIdx.x;
  int t = threadIdx.x;
  const float4* srow = (const float4*)(src + (size_t)row * DMODEL);
  float4 v = srow[t];
  if (res_copy) ((float4*)(res_copy + (size_t)row * DMODEL))[t] = v;
  float s = v.x + v.y + v.z + v.w;
  float sq = v.x * v.x + v.y * v.y + v.z * v.z + v.w * v.w;
  #pragma unroll
  for (int o = 32; o >= 1; o >>= 1) {
    s += __shfl_xor(s, o);
    sq += __shfl_xor(sq, o);
  }
  __shared__ float ss[4], ssq[4];
  int wid = t >> 6, lane = t & 63;
  if (lane == 0) { ss[wid] = s; ssq[wid] = sq; }
  __syncthreads();
  s = ss[0] + ss[1] + ss[2] + ss[3];
  sq = ssq[0] + ssq[1] + ssq[2] + ssq[3];
  float mu = s * (1.f / DMODEL);
  float var = sq * (1.f / DMODEL) - mu * mu;
  float rs = rsqrtf(var + LNEPS);
  float4 wv = ((const float4*)w)[t];
  float4 bv = ((const float4*)b)[t];
  float4 o4;
  o4.x = (v.x - mu) * rs * wv.x + bv.x;
  o4.y = (v.y - mu) * rs * wv.y + bv.y;
  o4.z = (v.z - mu) * rs * wv.z + bv.z;
  o4.w = (v.w - mu) * rs * wv.w + bv.w;
  if (OBF) {
    ushort4 ob;
    ob.x = f2bf(o4.x); ob.y = f2bf(o4.y); ob.z = f2bf(o4.z); ob.w = f2bf(o4.w);
    ((ushort4*)((unsigned short*)out + (size_t)row * DMODEL))[t] = ob;
  } else {
    ((float4*)((float*)out + (size_t)row * DMODEL))[t] = o4;
  }
}

__device__ __forceinline__ float softplus_f(float x) {
  return x > 20.f ? x : log1pf(expf(x));
}

// ---------------- bf16 MFMA GEMM, double-buffered prefetch (T3-min 2-phase) --
// act(A[M,K] @ W[N,K]^T [+bias]) [+add]; 128x128 tile, 4 waves, BK=32.
// PARTIAL: split-K slice — A/W k-offset = z*K, fp32 partial to slab z.
template<int ACT, bool BIAS, bool ADD, bool WF32, bool WBF, bool PARTIAL>
__global__ __launch_bounds__(256) void gemm_bf16(
    const unsigned short* __restrict__ A, int lda,
    const unsigned short* __restrict__ W, int ldw,
    float* __restrict__ C, int ldc, int K,
    const float* __restrict__ bias,
    const float* __restrict__ addsrc,
    unsigned short* __restrict__ Cb) {
  __shared__ unsigned short As[2][128][32];
  __shared__ unsigned short Ws[2][128][32];
  int t = threadIdx.x;
  int lane = t & 63, wave = t >> 6;
  int wr = wave >> 1, wc = wave & 1;
  int m0 = blockIdx.y * 128, n0 = blockIdx.x * 128;

  int kbase = 0;
  if (PARTIAL) {
    kbase = blockIdx.z * K;
    C += (size_t)blockIdx.z * (size_t)gridDim.y * 128 * ldc;
  }

  int r0 = t >> 2;               // 0..63
  int kk8 = (t & 3) << 3;        // 0,8,16,24
  const unsigned short* Ag = A + (size_t)(m0 + r0) * lda + kbase + kk8;
  const unsigned short* Wg = W + (size_t)(n0 + r0) * ldw + kbase + kk8;
  const size_t Astep = (size_t)64 * lda;
  const size_t Wstep = (size_t)64 * ldw;

  f32x4 zero = {0.f, 0.f, 0.f, 0.f};
  f32x4 acc[4][4];
  #pragma unroll
  for (int m = 0; m < 4; m++)
    #pragma unroll
    for (int n = 0; n < 4; n++) acc[m][n] = zero;

  int frow = lane & 15;
  int fk = (lane >> 4) << 3;

  auto stage = [&](int buf, int kt) {
    const unsigned short* ag = Ag + kt * 32;
    const unsigned short* wg = Wg + kt * 32;
    unsigned short* la = &As[buf][r0][kk8];
    unsigned short* lw = &Ws[buf][r0][kk8];
    gload16(ag, la);
    gload16(ag + Astep, la + 64 * 32);
    gload16(wg, lw);
    gload16(wg + Wstep, lw + 64 * 32);
  };
  auto compute = [&](int buf) {
    bf16x8 af[4], bw[4];
    #pragma unroll
    for (int m = 0; m < 4; m++)
      af[m] = *(const bf16x8*)&As[buf][wr * 64 + m * 16 + frow][fk];
    #pragma unroll
    for (int n = 0; n < 4; n++)
      bw[n] = *(const bf16x8*)&Ws[buf][wc * 64 + n * 16 + frow][fk];
    #pragma unroll
    for (int m = 0; m < 4; m++)
      #pragma unroll
      for (int n = 0; n < 4; n++)
        acc[m][n] = __builtin_amdgcn_mfma_f32_16x16x32_bf16(af[m], bw[n], acc[m][n], 0, 0, 0);
  };

  const int NT = K / 32;
  stage(0, 0);
  __syncthreads();                       // implicit vmcnt(0) drains prologue stage
  int cur = 0;
  for (int kt = 0; kt < NT - 1; ++kt) {
    stage(cur ^ 1, kt + 1);              // prefetch next tile (in flight during MFMA)
    compute(cur);
    __syncthreads();                     // single drain point per K-step
    cur ^= 1;
  }
  compute(cur);                          // last tile, no prefetch

  #pragma unroll
  for (int m = 0; m < 4; m++) {
    int rbase = m0 + wr * 64 + m * 16 + ((lane >> 4) << 2);
    #pragma unroll
    for (int n = 0; n < 4; n++) {
      int ccol = n0 + wc * 64 + n * 16 + (lane & 15);
      #pragma unroll
      for (int j = 0; j < 4; j++) {
        int crow = rbase + j;
        float v = acc[m][n][j];
        if (BIAS) v += bias[ccol];
        if (ACT == 1) v = softplus_f(v);
        if (ADD) v += addsrc[(size_t)crow * ldc + ccol];
        if (WF32 || PARTIAL) C[(size_t)crow * ldc + ccol] = v;
        if (WBF) Cb[(size_t)crow * ldc + ccol] = f2bf(v);
      }
    }
  }
}

// ---------------- split-K combine: xdbl = sum of 4 slabs (fp32 + bf16) -------
__global__ __launch_bounds__(256) void combine_xdbl(
    const float* __restrict__ part, float* __restrict__ xdbl,
    unsigned short* __restrict__ xdbl_bf) {
  int i = blockIdx.x * 256 + threadIdx.x;   // over ROWS*XP/4 = 131072
  const size_t slab = (size_t)ROWS * XP / 4;
  const float4* p = (const float4*)part;
  float4 a = p[i], b = p[i + slab], c = p[i + 2 * slab], d = p[i + 3 * slab];
  float4 s;
  s.x = a.x + b.x + c.x + d.x;
  s.y = a.y + b.y + c.y + d.y;
  s.z = a.z + b.z + c.z + d.z;
  s.w = a.w + b.w + c.w + d.w;
  ((float4*)xdbl)[i] = s;
  ushort4 o;
  o.x = f2bf(s.x); o.y = f2bf(s.y); o.z = f2bf(s.z); o.w = f2bf(s.w);
  ((ushort4*)xdbl_bf)[i] = o;
}

// ---------------- causal depthwise conv1d + SiLU (bf16 in, bf16 out) ---------
__global__ __launch_bounds__(256) void conv_silu_kernel(
    const unsigned short* __restrict__ xz, const float* __restrict__ cw,
    const float* __restrict__ cb, unsigned short* __restrict__ xbf) {
  int tid = blockIdx.x * 256 + threadIdx.x;
  int dv = tid & (DINNER / 4 - 1);
  int row = tid / (DINNER / 4);
  int l = row & (LSEQ - 1);
  int d = dv * 4;
  float acc0 = cb[d], acc1 = cb[d + 1], acc2 = cb[d + 2], acc3 = cb[d + 3];
  #pragma unroll
  for (int k = 0; k < DCONV; k++) {
    int ll = l - (DCONV - 1) + k;
    if (ll >= 0) {
      const ushort4 xv = *(const ushort4*)(xz + (size_t)(row - (DCONV - 1) + k) * (2 * DINNER) + d);
      acc0 = fmaf(bf2f(xv.x), cw[(d + 0) * DCONV + k], acc0);
      acc1 = fmaf(bf2f(xv.y), cw[(d + 1) * DCONV + k], acc1);
      acc2 = fmaf(bf2f(xv.z), cw[(d + 2) * DCONV + k], acc2);
      acc3 = fmaf(bf2f(xv.w), cw[(d + 3) * DCONV + k], acc3);
    }
  }
  float o0 = acc0 / (1.f + __expf(-acc0));
  float o1 = acc1 / (1.f + __expf(-acc1));
  float o2 = acc2 / (1.f + __expf(-acc2));
  float o3 = acc3 / (1.f + __expf(-acc3));
  ushort4 ob;
  ob.x = f2bf(o0); ob.y = f2bf(o1); ob.z = f2bf(o2); ob.w = f2bf(o3);
  *(ushort4*)(xbf + (size_t)row * DINNER + d) = ob;
}

// ================= chunk-parallel selective scan ============================
__global__ __launch_bounds__(256, 4) void scan_p1(
    const float* __restrict__ delta, const unsigned short* __restrict__ u,
    const float* __restrict__ xdbl, const float* __restrict__ A_log,
    float* __restrict__ aprodbuf, float* __restrict__ statebuf) {
  int tid = blockIdx.x * 256 + threadIdx.x;   // B*NCHUNK*DINNER = 262144
  int d = tid & (DINNER - 1);
  int chunk = (tid >> 11) & (NCHUNK - 1);
  int b = tid >> 17;
  float A[DSTATE], st[DSTATE], ap[DSTATE];
  #pragma unroll
  for (int s = 0; s < DSTATE; s++) {
    A[s] = -__expf(A_log[d * DSTATE + s]);
    st[s] = 0.f;
    ap[s] = 1.f;
  }
  int l0 = chunk * CLEN;
  const float* dptr = delta + ((size_t)b * LSEQ + l0) * DINNER + d;
  const unsigned short* uptr = u + ((size_t)b * LSEQ + l0) * DINNER + d;
  const float* xd = xdbl + ((size_t)b * LSEQ + l0) * XP;
  #pragma unroll 4
  for (int l = 0; l < CLEN; l++) {
    float dt = dptr[(size_t)l * DINNER];
    float uu = bf2f(uptr[(size_t)l * DINNER]);
    float du = dt * uu;
    #pragma unroll
    for (int s = 0; s < DSTATE; s++) {
      float dA = __expf(dt * A[s]);
      float Bv = xd[l * XP + 64 + s];
      st[s] = fmaf(dA, st[s], du * Bv);
      ap[s] *= dA;
    }
  }
  float4* apo = (float4*)(aprodbuf + (size_t)tid * DSTATE);
  float4* sto = (float4*)(statebuf + (size_t)tid * DSTATE);
  #pragma unroll
  for (int q = 0; q < 4; q++) {
    apo[q] = make_float4(ap[4 * q], ap[4 * q + 1], ap[4 * q + 2], ap[4 * q + 3]);
    sto[q] = make_float4(st[4 * q], st[4 * q + 1], st[4 * q + 2], st[4 * q + 3]);
  }
}

__global__ __launch_bounds__(256) void scan_p2(
    const float* __restrict__ aprodbuf, const float* __restrict__ statebuf,
    float* __restrict__ carryin) {
  int tid = blockIdx.x * 256 + threadIdx.x;   // B*DINNER*DSTATE = 65536
  int ds = tid & (DINNER * DSTATE - 1);
  int b = tid >> 15;
  float carry = 0.f;
  size_t base = (size_t)b * NCHUNK * DINNER * DSTATE + ds;
  for (int c = 0; c < NCHUNK; c++) {
    size_t idx = base + (size_t)c * (DINNER * DSTATE);
    carryin[idx] = carry;
    carry = fmaf(aprodbuf[idx], carry, statebuf[idx]);
  }
}

__global__ __launch_bounds__(256, 4) void scan_p3(
    const float* __restrict__ delta, const unsigned short* __restrict__ u,
    const float* __restrict__ xdbl, const unsigned short* __restrict__ xzbf,
    const float* __restrict__ A_log, const float* __restrict__ Dp,
    const float* __restrict__ carryin, unsigned short* __restrict__ ybf) {
  int tid = blockIdx.x * 256 + threadIdx.x;
  int d = tid & (DINNER - 1);
  int chunk = (tid >> 11) & (NCHUNK - 1);
  int b = tid >> 17;
  float A[DSTATE], st[DSTATE];
  const float4* ci = (const float4*)(carryin + (size_t)tid * DSTATE);
  #pragma unroll
  for (int q = 0; q < 4; q++) {
    float4 cv = ci[q];
    st[4 * q] = cv.x; st[4 * q + 1] = cv.y; st[4 * q + 2] = cv.z; st[4 * q + 3] = cv.w;
  }
  #pragma unroll
  for (int s = 0; s < DSTATE; s++) A[s] = -__expf(A_log[d * DSTATE + s]);
  float Dval = Dp[d];
  int l0 = chunk * CLEN;
  const float* dptr = delta + ((size_t)b * LSEQ + l0) * DINNER + d;
  const unsigned short* uptr = u + ((size_t)b * LSEQ + l0) * DINNER + d;
  const float* xd = xdbl + ((size_t)b * LSEQ + l0) * XP;
  const unsigned short* zptr = xzbf + ((size_t)b * LSEQ + l0) * (2 * DINNER) + DINNER + d;
  unsigned short* yptr = ybf + ((size_t)b * LSEQ + l0) * DINNER + d;
  #pragma unroll 4
  for (int l = 0; l < CLEN; l++) {
    float dt = dptr[(size_t)l * DINNER];
    float uu = bf2f(uptr[(size_t)l * DINNER]);
    float du = dt * uu;
    float acc = 0.f;
    #pragma unroll
    for (int s = 0; s < DSTATE; s++) {
      float dA = __expf(dt * A[s]);
      float Bv = xd[l * XP + 64 + s];
      float Cv = xd[l * XP + 80 + s];
      st[s] = fmaf(dA, st[s], du * Bv);
      acc = fmaf(st[s], Cv, acc);
    }
    float zz = bf2f(zptr[(size_t)l * (2 * DINNER)]);
    float yv = (acc + uu * Dval) * (zz / (1.f + __expf(-zz)));
    yptr[(size_t)l * DINNER] = f2bf(yv);
  }
}

extern "C" void kernel_launch(void* const* d_in, const int* in_sizes, int n_in,
                              void* d_out, int out_size, void* d_ws, size_t ws_size,
                              hipStream_t stream) {
  const float* hidden    = (const float*)d_in[0];
  const float* norm_w    = (const float*)d_in[1];
  const float* norm_b    = (const float*)d_in[2];
  const float* in_proj_w = (const float*)d_in[3];
  const float* conv_w    = (const float*)d_in[4];
  const float* conv_b    = (const float*)d_in[5];
  const float* x_proj_w  = (const float*)d_in[6];
  const float* dt_proj_w = (const float*)d_in[7];
  const float* dt_proj_b = (const float*)d_in[8];
  const float* A_log     = (const float*)d_in[9];
  const float* Dp        = (const float*)d_in[10];
  const float* out_proj_w= (const float*)d_in[11];
  const float* fnw       = (const float*)d_in[12];
  const float* fnb       = (const float*)d_in[13];
  float* out = (float*)d_out;

  // ---- workspace layout (≈162 MB; 190 MB proven safe last round) ----
  float* residual = (float*)d_ws;                                         // 16 MB
  float* delta    = residual + (size_t)ROWS * DMODEL;                     // 32 MB
  float* aprod    = delta + (size_t)ROWS * DINNER;                        // 16 MB
  float* statebuf = aprod + (size_t)NBATCH * NCHUNK * DINNER * DSTATE;    // 16 MB
  float* xdbl     = statebuf + (size_t)NBATCH * NCHUNK * DINNER * DSTATE; // 2 MB
  float* carryin  = xdbl + (size_t)ROWS * XP;                             // 16 MB
  float* fend     = carryin + (size_t)NBATCH * NCHUNK * DINNER * DSTATE;

  unsigned short* xz_bf   = (unsigned short*)fend;                        // 32 MB
  unsigned short* xbuf_bf = xz_bf + (size_t)ROWS * 2 * DINNER;            // 16 MB
  unsigned short* xdbl_bf = xbuf_bf + (size_t)ROWS * DINNER;              // 1 MB
  unsigned short* xpw_bf  = xdbl_bf + (size_t)ROWS * XP;                  // 2 MB
  unsigned short* dtw_bf  = xpw_bf + (size_t)N_LAYERS * XP * DINNER;      // 1 MB
  unsigned short* ipw_bf  = dtw_bf + (size_t)N_LAYERS * DINNER * DTRANK;  // 8 MB (per layer)
  unsigned short* opw_bf  = ipw_bf + (size_t)2 * DINNER * DMODEL;         // 4 MB (per layer)

  // overlays (lifetime-disjoint, stream-ordered):
  unsigned short* h_bf    = (unsigned short*)statebuf;  // LN->in_proj; dead before p1 writes
  unsigned short* ybuf_bf = (unsigned short*)aprod;     // p3 writes after p2 reads aprod
  float*          xpart   = delta;                      // split-K partials (8 MB of 32 MB); dead before dt_proj writes

  // one-time small weight conversions
  cvt_xpw<<<N_LAYERS * XP * DINNER / 4 / 256, 256, 0, stream>>>(x_proj_w, xpw_bf);
  {
    int n4 = N_LAYERS * DINNER * DTRANK / 4;
    cvt_f2bf<<<n4 / 256, 256, 0, stream>>>(dt_proj_w, dtw_bf, n4);
  }

  for (int i = 0; i < N_LAYERS; i++) {
    {
      int n4 = 2 * DINNER * DMODEL / 4;
      cvt_f2bf<<<n4 / 256, 256, 0, stream>>>(
          in_proj_w + (size_t)i * 2 * DINNER * DMODEL, ipw_bf, n4);
      n4 = DMODEL * DINNER / 4;
      cvt_f2bf<<<n4 / 256, 256, 0, stream>>>(
          out_proj_w + (size_t)i * DMODEL * DINNER, opw_bf, n4);
    }
    ln_kernel<true><<<ROWS, 256, 0, stream>>>(
        i == 0 ? hidden : residual, i == 0 ? residual : nullptr,
        norm_w + (size_t)i * DMODEL, norm_b + (size_t)i * DMODEL, h_bf);
    // in_proj -> xz bf16
    {
      dim3 g(2 * DINNER / 128, ROWS / 128);
      gemm_bf16<0, false, false, false, true, false><<<g, 256, 0, stream>>>(
          h_bf, DMODEL, ipw_bf, DMODEL, nullptr, 2 * DINNER, DMODEL,
          nullptr, nullptr, xz_bf);
    }
    conv_silu_kernel<<<(size_t)ROWS * DINNER / 4 / 256, 256, 0, stream>>>(
        xz_bf, conv_w + (size_t)i * DINNER * DCONV, conv_b + (size_t)i * DINNER,
        xbuf_bf);
    // x_proj: split-K (4 x K=512) -> partials, then combine -> xdbl fp32+bf16
    {
      dim3 g(1, ROWS / 128, NSLICE);
      gemm_bf16<0, false, false, true, false, true><<<g, 256, 0, stream>>>(
          xbuf_bf, DINNER, xpw_bf + (size_t)i * XP * DINNER, DINNER,
          xpart, XP, KSLICE, nullptr, nullptr, nullptr);
      combine_xdbl<<<ROWS * XP / 4 / 256, 256, 0, stream>>>(xpart, xdbl, xdbl_bf);
    }
    // dt_proj + bias + softplus -> delta fp32
    {
      dim3 g(DINNER / 128, ROWS / 128);
      gemm_bf16<1, true, false, true, false, false><<<g, 256, 0, stream>>>(
          xdbl_bf, XP, dtw_bf + (size_t)i * DINNER * DTRANK, DTRANK,
          delta, DINNER, DTRANK, dt_proj_b + (size_t)i * DINNER,
          nullptr, nullptr);
    }
    // chunk-parallel scan
    scan_p1<<<NBATCH * NCHUNK * DINNER / 256, 256, 0, stream>>>(
        delta, xbuf_bf, xdbl, A_log + (size_t)i * DINNER * DSTATE, aprod, statebuf);
    scan_p2<<<NBATCH * DINNER * DSTATE / 256, 256, 0, stream>>>(
        aprod, statebuf, carryin);
    scan_p3<<<NBATCH * NCHUNK * DINNER / 256, 256, 0, stream>>>(
        delta, xbuf_bf, xdbl, xz_bf, A_log + (size_t)i * DINNER * DSTATE,
        Dp + (size_t)i * DINNER, carryin, ybuf_bf);
    // out_proj + residual -> residual fp32
    {
      dim3 g(DMODEL / 128, ROWS / 128);
      gemm_bf16<0, false, true, true, false, false><<<g, 256, 0, stream>>>(
          ybuf_bf, DINNER, opw_bf, DINNER,
          residual, DMODEL, DINNER, nullptr, residual, nullptr);
    }
  }
  ln_kernel<false><<<ROWS, 256, 0, stream>>>(residual, nullptr, fnw, fnb, out);
}